// Round 1
// baseline (702.715 us; speedup 1.0000x reference)
//
#include <hip/hip_runtime.h>

#define F 128
#define TM 32
#define KC 32
#define NEG_SLOPE 0.01f

// ---------------- graph prep ----------------

__global__ __launch_bounds__(256) void deg_kernel(const int* __restrict__ dst,
                                                  int* __restrict__ deg, int E) {
    int e = blockIdx.x * 256 + threadIdx.x;
    if (e < E) atomicAdd(&deg[dst[e]], 1);
}

__global__ __launch_bounds__(256) void dis_kernel(const int* __restrict__ deg,
                                                  float* __restrict__ dis, int n) {
    int i = blockIdx.x * 256 + threadIdx.x;
    if (i < n) dis[i] = rsqrtf((float)deg[i] + 1.0f);  // +1 = self loop
}

// exclusive scan of deg -> offs (per-block partial), block totals -> bsum
__global__ __launch_bounds__(1024) void scan1(const int* __restrict__ deg,
                                              int* __restrict__ offs,
                                              int* __restrict__ bsum, int n) {
    __shared__ int tmp[1024];
    int tid = threadIdx.x;
    int idx = blockIdx.x * 1024 + tid;
    int v = (idx < n) ? deg[idx] : 0;
    int run = v;
    tmp[tid] = v;
    __syncthreads();
    for (int off = 1; off < 1024; off <<= 1) {
        int add = (tid >= off) ? tmp[tid - off] : 0;
        __syncthreads();
        run += add;
        tmp[tid] = run;
        __syncthreads();
    }
    if (idx < n) offs[idx] = run - v;          // exclusive, pre-base
    if (tid == 1023) bsum[blockIdx.x] = run;   // block total
}

__global__ void scan2(const int* __restrict__ bsum, int* __restrict__ bbase, int nb) {
    if (blockIdx.x == 0 && threadIdx.x == 0) {
        int run = 0;
        for (int b = 0; b < nb; ++b) { int t = bsum[b]; bbase[b] = run; run += t; }
    }
}

__global__ __launch_bounds__(1024) void scan3(int* __restrict__ offs,
                                              const int* __restrict__ bbase,
                                              int* __restrict__ cursor, int n) {
    int idx = blockIdx.x * 1024 + threadIdx.x;
    if (idx < n) {
        int o = offs[idx] + bbase[blockIdx.x];
        offs[idx] = o;
        cursor[idx] = o;
    }
}

__global__ __launch_bounds__(256) void fill_kernel(const int* __restrict__ src,
                                                   const int* __restrict__ dst,
                                                   const float* __restrict__ dis,
                                                   int* __restrict__ cursor,
                                                   int* __restrict__ src_sorted,
                                                   float* __restrict__ norm_sorted,
                                                   int E) {
    int e = blockIdx.x * 256 + threadIdx.x;
    if (e < E) {
        int s = src[e], d = dst[e];
        int pos = atomicAdd(&cursor[d], 1);
        src_sorted[pos] = s;
        norm_sorted[pos] = dis[s] * dis[d];
    }
}

// ---------------- GEMM: out = in @ W.T  (W is [128 out][128 in] row-major) ----
// Safe when in == out: all reads of `in` precede the final barrier, all writes follow.

__global__ __launch_bounds__(256) void gemm_xwt(const float* in,
                                                const float* __restrict__ W,
                                                float* out, int n) {
    __shared__ __align__(16) float Wt[KC][F + 4];   // [k][c], stride 132 (16B-aligned rows)
    __shared__ float xs[TM][KC + 1];                // [row][k]
    int tid = threadIdx.x;
    int row0 = blockIdx.x * TM;
    int c4 = (tid & 31) * 4;        // 4 output cols
    int rg = (tid >> 5) * 4;        // 4 rows

    float acc[4][4];
#pragma unroll
    for (int j = 0; j < 4; ++j)
#pragma unroll
        for (int i = 0; i < 4; ++i) acc[j][i] = 0.f;

    for (int k0 = 0; k0 < F; k0 += KC) {
        __syncthreads();
        // stage W chunk transposed: 128 cols x 32 k
#pragma unroll
        for (int i = 0; i < 16; ++i) {
            int idx = i * 256 + tid;
            int kc = idx & 31;
            int c  = idx >> 5;
            Wt[kc][c] = W[c * F + k0 + kc];
        }
        // stage x rows chunk: 32 rows x 32 k
#pragma unroll
        for (int i = 0; i < 4; ++i) {
            int idx = i * 256 + tid;
            int kc = idx & 31;
            int r  = idx >> 5;
            xs[r][kc] = in[(row0 + r) * F + k0 + kc];
        }
        __syncthreads();
#pragma unroll 8
        for (int kc = 0; kc < KC; ++kc) {
            float4 w4 = *(const float4*)&Wt[kc][c4];
#pragma unroll
            for (int j = 0; j < 4; ++j) {
                float xv = xs[rg + j][kc];
                acc[j][0] += xv * w4.x;
                acc[j][1] += xv * w4.y;
                acc[j][2] += xv * w4.z;
                acc[j][3] += xv * w4.w;
            }
        }
    }
#pragma unroll
    for (int j = 0; j < 4; ++j) {
        float4 o;
        o.x = acc[j][0]; o.y = acc[j][1]; o.z = acc[j][2]; o.w = acc[j][3];
        *(float4*)&out[(row0 + rg + j) * F + c4] = o;
    }
}

// ---------------- aggregation: out = lrelu(sum_e norm*h[src] + h*selfw + b) ----

__global__ __launch_bounds__(256) void agg_kernel(const float* __restrict__ h,
                                                  const float* __restrict__ dis,
                                                  const float* __restrict__ bias,
                                                  const int* __restrict__ src_sorted,
                                                  const float* __restrict__ norm_sorted,
                                                  const int* __restrict__ offs,
                                                  float* __restrict__ out,
                                                  int n, int E) {
    int node = blockIdx.x * 2 + (threadIdx.x >> 7);  // 2 nodes per block
    int f = threadIdx.x & 127;
    if (node >= n) return;
    int beg = offs[node];
    int end = (node + 1 < n) ? offs[node + 1] : E;
    float di = dis[node];
    float acc = h[node * F + f] * (di * di);   // self-loop term: h_i / deg_i
    int e = beg;
    for (; e + 4 <= end; e += 4) {
        int s0 = src_sorted[e + 0], s1 = src_sorted[e + 1];
        int s2 = src_sorted[e + 2], s3 = src_sorted[e + 3];
        float w0 = norm_sorted[e + 0], w1 = norm_sorted[e + 1];
        float w2 = norm_sorted[e + 2], w3 = norm_sorted[e + 3];
        acc += h[s0 * F + f] * w0;
        acc += h[s1 * F + f] * w1;
        acc += h[s2 * F + f] * w2;
        acc += h[s3 * F + f] * w3;
    }
    for (; e < end; ++e) {
        acc += h[src_sorted[e] * F + f] * norm_sorted[e];
    }
    acc += bias[f];
    out[node * F + f] = (acc > 0.f) ? acc : acc * NEG_SLOPE;
}

// ---------------- launch ----------------

static inline size_t alup(size_t x) { return (x + 255) & ~(size_t)255; }

extern "C" void kernel_launch(void* const* d_in, const int* in_sizes, int n_in,
                              void* d_out, int out_size, void* d_ws, size_t ws_size,
                              hipStream_t stream) {
    const float* x  = (const float*)d_in[0];
    const int*   ei = (const int*)d_in[1];
    const float* W1 = (const float*)d_in[2];
    const float* b1 = (const float*)d_in[3];
    const float* W2 = (const float*)d_in[4];
    const float* b2 = (const float*)d_in[5];
    float* out = (float*)d_out;

    const int N = in_sizes[0] / F;    // 100000
    const int E = in_sizes[1] / 2;    // 1600000
    const int* src = ei;
    const int* dst = ei + E;

    char* p = (char*)d_ws;
    int*   deg         = (int*)p;   p += alup((size_t)N * 4);
    int*   offs        = (int*)p;   p += alup((size_t)N * 4);
    int*   cursor      = (int*)p;   p += alup((size_t)N * 4);
    int*   bsum        = (int*)p;   p += alup(128 * 4);
    int*   bbase       = (int*)p;   p += alup(128 * 4);
    float* dis         = (float*)p; p += alup((size_t)N * 4);
    int*   src_sorted  = (int*)p;   p += alup((size_t)E * 4);
    float* norm_sorted = (float*)p; p += alup((size_t)E * 4);
    float* g           = (float*)p; p += alup((size_t)N * F * 4);

    const int nb = (N + 1023) / 1024;  // 98

    hipMemsetAsync(deg, 0, (size_t)N * 4, stream);
    deg_kernel<<<(E + 255) / 256, 256, 0, stream>>>(dst, deg, E);
    dis_kernel<<<(N + 255) / 256, 256, 0, stream>>>(deg, dis, N);
    scan1<<<nb, 1024, 0, stream>>>(deg, offs, bsum, N);
    scan2<<<1, 64, 0, stream>>>(bsum, bbase, nb);
    scan3<<<nb, 1024, 0, stream>>>(offs, bbase, cursor, N);
    fill_kernel<<<(E + 255) / 256, 256, 0, stream>>>(src, dst, dis, cursor,
                                                     src_sorted, norm_sorted, E);

    // layer 1: h1 = x @ W1.T  -> d_out (scratch use), agg -> g (with lrelu)
    gemm_xwt<<<N / TM, 256, 0, stream>>>(x, W1, out, N);
    agg_kernel<<<(N + 1) / 2, 256, 0, stream>>>(out, dis, b1, src_sorted, norm_sorted,
                                                offs, g, N, E);
    // layer 2: h2 = g @ W2.T in-place, agg -> d_out (with lrelu)
    gemm_xwt<<<N / TM, 256, 0, stream>>>(g, W2, g, N);
    agg_kernel<<<(N + 1) / 2, 256, 0, stream>>>(g, dis, b2, src_sorted, norm_sorted,
                                                offs, out, N, E);
}

// Round 2
// 607.355 us; speedup vs baseline: 1.1570x; 1.1570x over previous
//
#include <hip/hip_runtime.h>

#define F 128
#define TM 32
#define KC 32
#define NEG_SLOPE 0.01f

// ---------------- graph prep ----------------

__global__ __launch_bounds__(256) void deg_kernel(const int* __restrict__ dst,
                                                  int* __restrict__ deg, int E) {
    int e = blockIdx.x * 256 + threadIdx.x;
    if (e < E) atomicAdd(&deg[dst[e]], 1);
}

__global__ __launch_bounds__(256) void dis_kernel(const int* __restrict__ deg,
                                                  float* __restrict__ dis, int n) {
    int i = blockIdx.x * 256 + threadIdx.x;
    if (i < n) dis[i] = rsqrtf((float)deg[i] + 1.0f);  // +1 = self loop
}

// exclusive scan of deg -> offs (per-block partial), block totals -> bsum
__global__ __launch_bounds__(1024) void scan1(const int* __restrict__ deg,
                                              int* __restrict__ offs,
                                              int* __restrict__ bsum, int n) {
    __shared__ int tmp[1024];
    int tid = threadIdx.x;
    int idx = blockIdx.x * 1024 + tid;
    int v = (idx < n) ? deg[idx] : 0;
    int run = v;
    tmp[tid] = v;
    __syncthreads();
    for (int off = 1; off < 1024; off <<= 1) {
        int add = (tid >= off) ? tmp[tid - off] : 0;
        __syncthreads();
        run += add;
        tmp[tid] = run;
        __syncthreads();
    }
    if (idx < n) offs[idx] = run - v;          // exclusive, pre-base
    if (tid == 1023) bsum[blockIdx.x] = run;   // block total
}

__global__ __launch_bounds__(128) void scan2(const int* __restrict__ bsum,
                                             int* __restrict__ bbase, int nb) {
    __shared__ int tmp[128];
    int tid = threadIdx.x;
    int v0 = (tid < nb) ? bsum[tid] : 0;
    int v = v0;
    tmp[tid] = v;
    __syncthreads();
    for (int off = 1; off < 128; off <<= 1) {
        int add = (tid >= off) ? tmp[tid - off] : 0;
        __syncthreads();
        v += add;
        tmp[tid] = v;
        __syncthreads();
    }
    if (tid < nb) bbase[tid] = v - v0;  // exclusive
}

__global__ __launch_bounds__(1024) void scan3(int* __restrict__ offs,
                                              const int* __restrict__ bbase,
                                              int* __restrict__ cursor, int n) {
    int idx = blockIdx.x * 1024 + threadIdx.x;
    if (idx < n) {
        int o = offs[idx] + bbase[blockIdx.x];
        offs[idx] = o;
        cursor[idx] = o;
    }
}

// pack (src, norm) into one 8B record -> single scattered store per edge
__global__ __launch_bounds__(256) void fill_kernel(const int* __restrict__ src,
                                                   const int* __restrict__ dst,
                                                   const float* __restrict__ dis,
                                                   int* __restrict__ cursor,
                                                   int2* __restrict__ edges,
                                                   int E) {
    int e = blockIdx.x * 256 + threadIdx.x;
    if (e < E) {
        int s = src[e], d = dst[e];
        int pos = atomicAdd(&cursor[d], 1);
        edges[pos] = make_int2(s, __float_as_int(dis[s] * dis[d]));
    }
}

// ---------------- GEMM: out = in @ W.T  (W is [128 out][128 in] row-major) ----
// Safe when in == out: each block only reads its own 32 rows (staged to LDS
// before the post-staging barrier) and writes them after all compute.

__global__ __launch_bounds__(256) void gemm_xwt(const float* in,
                                                const float* __restrict__ W,
                                                float* out, int n) {
    __shared__ __align__(16) float Wt[KC][F + 4];   // [k][c], stride 132 floats
    __shared__ __align__(16) float xs[TM][KC + 4];  // [row][k], stride 36 floats
    int tid = threadIdx.x;
    int row0 = blockIdx.x * TM;
    int c4 = (tid & 31) * 4;        // 4 output cols
    int rg = (tid >> 5) * 4;        // 4 rows

    float acc[4][4];
#pragma unroll
    for (int j = 0; j < 4; ++j)
#pragma unroll
        for (int i = 0; i < 4; ++i) acc[j][i] = 0.f;

    for (int k0 = 0; k0 < F; k0 += KC) {
        __syncthreads();
        // stage W chunk transposed: 128 cols x 32 k (coalesced global reads)
#pragma unroll
        for (int i = 0; i < 16; ++i) {
            int idx = i * 256 + tid;
            int kc = idx & 31;
            int c  = idx >> 5;
            Wt[kc][c] = W[c * F + k0 + kc];
        }
        // stage x rows chunk: 32 rows x 32 k (natural layout, conflict-free)
#pragma unroll
        for (int i = 0; i < 4; ++i) {
            int idx = i * 256 + tid;
            int kc = idx & 31;
            int r  = idx >> 5;
            xs[r][kc] = in[(size_t)(row0 + r) * F + k0 + kc];
        }
        __syncthreads();
        // k-blocked 4x4x4 micro-kernel: all LDS traffic is ds_read_b128
#pragma unroll
        for (int kc4 = 0; kc4 < KC; kc4 += 4) {
            float4 xv[4];
#pragma unroll
            for (int j = 0; j < 4; ++j) xv[j] = *(const float4*)&xs[rg + j][kc4];
#pragma unroll
            for (int ik = 0; ik < 4; ++ik) {
                float4 w4 = *(const float4*)&Wt[kc4 + ik][c4];
#pragma unroll
                for (int j = 0; j < 4; ++j) {
                    float xvv = (ik == 0) ? xv[j].x : (ik == 1) ? xv[j].y
                              : (ik == 2) ? xv[j].z : xv[j].w;
                    acc[j][0] += xvv * w4.x;
                    acc[j][1] += xvv * w4.y;
                    acc[j][2] += xvv * w4.z;
                    acc[j][3] += xvv * w4.w;
                }
            }
        }
    }
#pragma unroll
    for (int j = 0; j < 4; ++j) {
        float4 o;
        o.x = acc[j][0]; o.y = acc[j][1]; o.z = acc[j][2]; o.w = acc[j][3];
        *(float4*)&out[(size_t)(row0 + rg + j) * F + c4] = o;
    }
}

// ---------------- aggregation: out = lrelu(sum_e norm*h[src] + h*selfw + b) ----
// one wave per node, float2 per lane (64 lanes x 2 = 128 features)

__global__ __launch_bounds__(256) void agg_kernel(const float2* __restrict__ h2,
                                                  const float* __restrict__ dis,
                                                  const float* __restrict__ bias,
                                                  const int2* __restrict__ edges,
                                                  const int* __restrict__ offs,
                                                  float2* __restrict__ out,
                                                  int n, int E) {
    int node = blockIdx.x * 4 + (threadIdx.x >> 6);
    int lane = threadIdx.x & 63;
    if (node >= n) return;
    int beg = offs[node];
    int end = (node + 1 < n) ? offs[node + 1] : E;
    float di = dis[node];
    float sw = di * di;                         // self-loop weight 1/deg
    float2 hv = h2[(size_t)node * 64 + lane];
    float ax = hv.x * sw, ay = hv.y * sw;
    int e = beg;
    for (; e + 4 <= end; e += 4) {
        int2 e0 = edges[e + 0], e1 = edges[e + 1];
        int2 e2 = edges[e + 2], e3 = edges[e + 3];
        float2 a0 = h2[(size_t)e0.x * 64 + lane];
        float2 a1 = h2[(size_t)e1.x * 64 + lane];
        float2 a2 = h2[(size_t)e2.x * 64 + lane];
        float2 a3 = h2[(size_t)e3.x * 64 + lane];
        float w0 = __int_as_float(e0.y), w1 = __int_as_float(e1.y);
        float w2 = __int_as_float(e2.y), w3 = __int_as_float(e3.y);
        ax += a0.x * w0; ay += a0.y * w0;
        ax += a1.x * w1; ay += a1.y * w1;
        ax += a2.x * w2; ay += a2.y * w2;
        ax += a3.x * w3; ay += a3.y * w3;
    }
    for (; e < end; ++e) {
        int2 er = edges[e];
        float2 a = h2[(size_t)er.x * 64 + lane];
        float w = __int_as_float(er.y);
        ax += a.x * w; ay += a.y * w;
    }
    float2 b = ((const float2*)bias)[lane];
    ax += b.x; ay += b.y;
    ax = (ax > 0.f) ? ax : ax * NEG_SLOPE;
    ay = (ay > 0.f) ? ay : ay * NEG_SLOPE;
    out[(size_t)node * 64 + lane] = make_float2(ax, ay);
}

// ---------------- launch ----------------

static inline size_t alup(size_t x) { return (x + 255) & ~(size_t)255; }

extern "C" void kernel_launch(void* const* d_in, const int* in_sizes, int n_in,
                              void* d_out, int out_size, void* d_ws, size_t ws_size,
                              hipStream_t stream) {
    const float* x  = (const float*)d_in[0];
    const int*   ei = (const int*)d_in[1];
    const float* W1 = (const float*)d_in[2];
    const float* b1 = (const float*)d_in[3];
    const float* W2 = (const float*)d_in[4];
    const float* b2 = (const float*)d_in[5];
    float* out = (float*)d_out;

    const int N = in_sizes[0] / F;    // 100000
    const int E = in_sizes[1] / 2;    // 1600000
    const int* src = ei;
    const int* dst = ei + E;

    char* p = (char*)d_ws;
    int*   deg    = (int*)p;   p += alup((size_t)N * 4);
    int*   offs   = (int*)p;   p += alup((size_t)N * 4);
    int*   cursor = (int*)p;   p += alup((size_t)N * 4);
    int*   bsum   = (int*)p;   p += alup(128 * 4);
    int*   bbase  = (int*)p;   p += alup(128 * 4);
    float* dis    = (float*)p; p += alup((size_t)N * 4);
    int2*  edges  = (int2*)p;  p += alup((size_t)E * 8);
    float* g      = (float*)p; p += alup((size_t)N * F * 4);

    const int nb = (N + 1023) / 1024;  // 98

    hipMemsetAsync(deg, 0, (size_t)N * 4, stream);
    deg_kernel<<<(E + 255) / 256, 256, 0, stream>>>(dst, deg, E);
    dis_kernel<<<(N + 255) / 256, 256, 0, stream>>>(deg, dis, N);
    scan1<<<nb, 1024, 0, stream>>>(deg, offs, bsum, N);
    scan2<<<1, 128, 0, stream>>>(bsum, bbase, nb);
    scan3<<<nb, 1024, 0, stream>>>(offs, bbase, cursor, N);
    fill_kernel<<<(E + 255) / 256, 256, 0, stream>>>(src, dst, dis, cursor, edges, E);

    // layer 1: h1 = x @ W1.T -> d_out (scratch), agg(+bias+lrelu) -> g
    gemm_xwt<<<N / TM, 256, 0, stream>>>(x, W1, out, N);
    agg_kernel<<<(N + 3) / 4, 256, 0, stream>>>((const float2*)out, dis, b1, edges,
                                                offs, (float2*)g, N, E);
    // layer 2: h2 = g @ W2.T in-place, agg(+bias+lrelu) -> d_out
    gemm_xwt<<<N / TM, 256, 0, stream>>>(g, W2, g, N);
    agg_kernel<<<(N + 3) / 4, 256, 0, stream>>>((const float2*)g, dis, b2, edges,
                                                offs, (float2*)out, N, E);
}

// Round 3
// 495.578 us; speedup vs baseline: 1.4180x; 1.2255x over previous
//
#include <hip/hip_runtime.h>

#define F 128
#define NEG_SLOPE 0.01f

typedef _Float16 half2_t __attribute__((ext_vector_type(2)));
typedef _Float16 half4_t __attribute__((ext_vector_type(4)));
typedef _Float16 half8_t __attribute__((ext_vector_type(8)));
typedef float f32x4 __attribute__((ext_vector_type(4)));

// ---------------- graph prep ----------------

__global__ __launch_bounds__(256) void deg_kernel(const int* __restrict__ dst,
                                                  int* __restrict__ deg, int E) {
    int e = blockIdx.x * 256 + threadIdx.x;
    if (e < E) atomicAdd(&deg[dst[e]], 1);
}

__global__ __launch_bounds__(256) void dis_kernel(const int* __restrict__ deg,
                                                  float* __restrict__ dis, int n) {
    int i = blockIdx.x * 256 + threadIdx.x;
    if (i < n) dis[i] = rsqrtf((float)deg[i] + 1.0f);  // +1 = self loop
}

__global__ __launch_bounds__(1024) void scan1(const int* __restrict__ deg,
                                              int* __restrict__ offs,
                                              int* __restrict__ bsum, int n) {
    __shared__ int tmp[1024];
    int tid = threadIdx.x;
    int idx = blockIdx.x * 1024 + tid;
    int v = (idx < n) ? deg[idx] : 0;
    int run = v;
    tmp[tid] = v;
    __syncthreads();
    for (int off = 1; off < 1024; off <<= 1) {
        int add = (tid >= off) ? tmp[tid - off] : 0;
        __syncthreads();
        run += add;
        tmp[tid] = run;
        __syncthreads();
    }
    if (idx < n) offs[idx] = run - v;          // exclusive, pre-base
    if (tid == 1023) bsum[blockIdx.x] = run;   // block total
}

__global__ __launch_bounds__(128) void scan2(const int* __restrict__ bsum,
                                             int* __restrict__ bbase, int nb) {
    __shared__ int tmp[128];
    int tid = threadIdx.x;
    int v0 = (tid < nb) ? bsum[tid] : 0;
    int v = v0;
    tmp[tid] = v;
    __syncthreads();
    for (int off = 1; off < 128; off <<= 1) {
        int add = (tid >= off) ? tmp[tid - off] : 0;
        __syncthreads();
        v += add;
        tmp[tid] = v;
        __syncthreads();
    }
    if (tid < nb) bbase[tid] = v - v0;  // exclusive
}

__global__ __launch_bounds__(1024) void scan3(int* __restrict__ offs,
                                              const int* __restrict__ bbase,
                                              int* __restrict__ cursor, int n) {
    int idx = blockIdx.x * 1024 + threadIdx.x;
    if (idx < n) {
        int o = offs[idx] + bbase[blockIdx.x];
        offs[idx] = o;
        cursor[idx] = o;
    }
}

__global__ __launch_bounds__(256) void fill_kernel(const int* __restrict__ src,
                                                   const int* __restrict__ dst,
                                                   const float* __restrict__ dis,
                                                   int* __restrict__ cursor,
                                                   int2* __restrict__ edges,
                                                   int E) {
    int e = blockIdx.x * 256 + threadIdx.x;
    if (e < E) {
        int s = src[e], d = dst[e];
        int pos = atomicAdd(&cursor[d], 1);
        edges[pos] = make_int2(s, __float_as_int(dis[s] * dis[d]));
    }
}

// ---------------- fp32 -> fp16 convert (n multiple of 4) ----------------

__global__ __launch_bounds__(256) void cvt_f2h(const float* __restrict__ in,
                                               _Float16* __restrict__ out, int n4) {
    int i = blockIdx.x * 256 + threadIdx.x;
    if (i < n4) {
        float4 v = ((const float4*)in)[i];
        half4_t h;
        h.x = (_Float16)v.x; h.y = (_Float16)v.y;
        h.z = (_Float16)v.z; h.w = (_Float16)v.w;
        ((half4_t*)out)[i] = h;
    }
}

// ---------------- GEMM: out = A @ W.T via f16 MFMA ----------------
// A: [n][128] fp16 row-major. W: [128 out][128 in] fp16 row-major.
// Per wave: one 16-row tile x full 128 cols. W fragments register-resident.
// MFMA layouts: A[m=lane&15][k=quad*8+j]; B[n=lane&15][k=quad*8+j] (= W[n][k]);
// C/D: col=lane&15, row=quad*4+reg.

__global__ __launch_bounds__(256) void gemm_mfma(const _Float16* __restrict__ A,
                                                 const _Float16* __restrict__ Wh,
                                                 _Float16* __restrict__ out,
                                                 int ntiles) {
    int wave = threadIdx.x >> 6;
    int lane = threadIdx.x & 63;
    int tile = blockIdx.x * 4 + wave;
    if (tile >= ntiles) return;
    int m = lane & 15;
    int quad = lane >> 4;

    half8_t bfrag[8][4];
#pragma unroll
    for (int t = 0; t < 8; ++t)
#pragma unroll
        for (int c = 0; c < 4; ++c)
            bfrag[t][c] = *(const half8_t*)&Wh[(t * 16 + m) * F + c * 32 + quad * 8];

    const _Float16* arow = A + (size_t)tile * 16 * F;
    half8_t afrag[4];
#pragma unroll
    for (int c = 0; c < 4; ++c)
        afrag[c] = *(const half8_t*)&arow[m * F + c * 32 + quad * 8];

    f32x4 acc[8];
#pragma unroll
    for (int t = 0; t < 8; ++t) acc[t] = (f32x4){0.f, 0.f, 0.f, 0.f};

#pragma unroll
    for (int c = 0; c < 4; ++c)
#pragma unroll
        for (int t = 0; t < 8; ++t)
            acc[t] = __builtin_amdgcn_mfma_f32_16x16x32_f16(afrag[c], bfrag[t][c],
                                                            acc[t], 0, 0, 0);

    _Float16* orow = out + (size_t)tile * 16 * F;
#pragma unroll
    for (int t = 0; t < 8; ++t)
#pragma unroll
        for (int r = 0; r < 4; ++r)
            orow[(quad * 4 + r) * F + t * 16 + m] = (_Float16)acc[t][r];
}

// ---------------- aggregation ----------------
// one wave per node; 64 lanes x half2 = 128 features; fp16 gathers.

#define AGG_BODY                                                               \
    int node = blockIdx.x * 4 + (threadIdx.x >> 6);                            \
    int lane = threadIdx.x & 63;                                               \
    if (node >= n) return;                                                     \
    int beg = offs[node];                                                      \
    int end = (node + 1 < n) ? offs[node + 1] : E;                             \
    float di = dis[node];                                                      \
    float sw = di * di;                                                        \
    half2_t hv = h2[(size_t)node * 64 + lane];                                 \
    float ax = (float)hv.x * sw, ay = (float)hv.y * sw;                        \
    int e = beg;                                                               \
    for (; e + 4 <= end; e += 4) {                                             \
        int2 e0 = edges[e + 0], e1 = edges[e + 1];                             \
        int2 e2 = edges[e + 2], e3 = edges[e + 3];                             \
        half2_t a0 = h2[(size_t)e0.x * 64 + lane];                             \
        half2_t a1 = h2[(size_t)e1.x * 64 + lane];                             \
        half2_t a2 = h2[(size_t)e2.x * 64 + lane];                             \
        half2_t a3 = h2[(size_t)e3.x * 64 + lane];                             \
        float w0 = __int_as_float(e0.y), w1 = __int_as_float(e1.y);            \
        float w2 = __int_as_float(e2.y), w3 = __int_as_float(e3.y);            \
        ax += (float)a0.x * w0; ay += (float)a0.y * w0;                        \
        ax += (float)a1.x * w1; ay += (float)a1.y * w1;                        \
        ax += (float)a2.x * w2; ay += (float)a2.y * w2;                        \
        ax += (float)a3.x * w3; ay += (float)a3.y * w3;                        \
    }                                                                          \
    for (; e < end; ++e) {                                                     \
        int2 er = edges[e];                                                    \
        half2_t a = h2[(size_t)er.x * 64 + lane];                              \
        float w = __int_as_float(er.y);                                        \
        ax += (float)a.x * w; ay += (float)a.y * w;                            \
    }                                                                          \
    float2 b = ((const float2*)bias)[lane];                                    \
    ax += b.x; ay += b.y;                                                      \
    ax = (ax > 0.f) ? ax : ax * NEG_SLOPE;                                     \
    ay = (ay > 0.f) ? ay : ay * NEG_SLOPE;

// layer-1 variant: writes fp16 (feeds next GEMM)
__global__ __launch_bounds__(256) void agg_to_h(const half2_t* __restrict__ h2,
                                                const float* __restrict__ dis,
                                                const float* __restrict__ bias,
                                                const int2* __restrict__ edges,
                                                const int* __restrict__ offs,
                                                half2_t* __restrict__ out,
                                                int n, int E) {
    AGG_BODY
    half2_t o; o.x = (_Float16)ax; o.y = (_Float16)ay;
    out[(size_t)node * 64 + lane] = o;
}

// layer-2 variant: writes fp32 (final output)
__global__ __launch_bounds__(256) void agg_to_f(const half2_t* __restrict__ h2,
                                                const float* __restrict__ dis,
                                                const float* __restrict__ bias,
                                                const int2* __restrict__ edges,
                                                const int* __restrict__ offs,
                                                float2* __restrict__ out,
                                                int n, int E) {
    AGG_BODY
    out[(size_t)node * 64 + lane] = make_float2(ax, ay);
}

// ---------------- launch ----------------

static inline size_t alup(size_t x) { return (x + 255) & ~(size_t)255; }

extern "C" void kernel_launch(void* const* d_in, const int* in_sizes, int n_in,
                              void* d_out, int out_size, void* d_ws, size_t ws_size,
                              hipStream_t stream) {
    const float* x  = (const float*)d_in[0];
    const int*   ei = (const int*)d_in[1];
    const float* W1 = (const float*)d_in[2];
    const float* b1 = (const float*)d_in[3];
    const float* W2 = (const float*)d_in[4];
    const float* b2 = (const float*)d_in[5];
    float* out = (float*)d_out;

    const int N = in_sizes[0] / F;    // 100000
    const int E = in_sizes[1] / 2;    // 1600000
    const int* src = ei;
    const int* dst = ei + E;

    char* p = (char*)d_ws;
    int*      deg    = (int*)p;      p += alup((size_t)N * 4);
    int*      offs   = (int*)p;      p += alup((size_t)N * 4);
    int*      cursor = (int*)p;      p += alup((size_t)N * 4);
    int*      bsum   = (int*)p;      p += alup(128 * 4);
    int*      bbase  = (int*)p;      p += alup(128 * 4);
    float*    dis    = (float*)p;    p += alup((size_t)N * 4);
    int2*     edges  = (int2*)p;     p += alup((size_t)E * 8);
    _Float16* xg     = (_Float16*)p; p += alup((size_t)N * F * 2);  // x, then g
    _Float16* hh     = (_Float16*)p; p += alup((size_t)N * F * 2);  // h (both layers)
    _Float16* W1h    = (_Float16*)p; p += alup((size_t)F * F * 2);
    _Float16* W2h    = (_Float16*)p; p += alup((size_t)F * F * 2);

    const int nb = (N + 1023) / 1024;      // 98
    const int ntiles = (N + 15) / 16;      // 6250
    const int gemm_grid = (ntiles + 3) / 4;

    hipMemsetAsync(deg, 0, (size_t)N * 4, stream);
    deg_kernel<<<(E + 255) / 256, 256, 0, stream>>>(dst, deg, E);
    dis_kernel<<<(N + 255) / 256, 256, 0, stream>>>(deg, dis, N);
    scan1<<<nb, 1024, 0, stream>>>(deg, offs, bsum, N);
    scan2<<<1, 128, 0, stream>>>(bsum, bbase, nb);
    scan3<<<nb, 1024, 0, stream>>>(offs, bbase, cursor, N);
    fill_kernel<<<(E + 255) / 256, 256, 0, stream>>>(src, dst, dis, cursor, edges, E);

    // convert inputs to fp16
    cvt_f2h<<<(N * F / 4 + 255) / 256, 256, 0, stream>>>(x, xg, N * F / 4);
    cvt_f2h<<<(F * F / 4 + 255) / 256, 256, 0, stream>>>(W1, W1h, F * F / 4);
    cvt_f2h<<<(F * F / 4 + 255) / 256, 256, 0, stream>>>(W2, W2h, F * F / 4);

    // layer 1: h = x @ W1.T (fp16), agg(+b1+lrelu) -> g (fp16, overwrites xg)
    gemm_mfma<<<gemm_grid, 256, 0, stream>>>(xg, W1h, hh, ntiles);
    agg_to_h<<<(N + 3) / 4, 256, 0, stream>>>((const half2_t*)hh, dis, b1, edges,
                                              offs, (half2_t*)xg, N, E);
    // layer 2: h = g @ W2.T (fp16), agg(+b2+lrelu) -> d_out (fp32)
    gemm_mfma<<<gemm_grid, 256, 0, stream>>>(xg, W2h, hh, ntiles);
    agg_to_f<<<(N + 3) / 4, 256, 0, stream>>>((const half2_t*)hh, dis, b2, edges,
                                              offs, (float2*)out, N, E);
}

// Round 4
// 458.430 us; speedup vs baseline: 1.5329x; 1.0810x over previous
//
#include <hip/hip_runtime.h>

#define F 128
#define NEG_SLOPE 0.01f

typedef _Float16 half8_t __attribute__((ext_vector_type(8)));
typedef float f32x4 __attribute__((ext_vector_type(4)));

// ---------------- graph prep ----------------

__global__ __launch_bounds__(256) void deg_kernel(const int* __restrict__ dst,
                                                  int* __restrict__ deg, int E) {
    int e = blockIdx.x * 256 + threadIdx.x;
    if (e < E) atomicAdd(&deg[dst[e]], 1);
}

// scan1 also produces dis = rsqrt(deg+1)
__global__ __launch_bounds__(1024) void scan1(const int* __restrict__ deg,
                                              int* __restrict__ offs,
                                              int* __restrict__ bsum,
                                              float* __restrict__ dis, int n) {
    __shared__ int tmp[1024];
    int tid = threadIdx.x;
    int idx = blockIdx.x * 1024 + tid;
    int v = (idx < n) ? deg[idx] : 0;
    if (idx < n) dis[idx] = rsqrtf((float)v + 1.0f);
    int run = v;
    tmp[tid] = v;
    __syncthreads();
    for (int off = 1; off < 1024; off <<= 1) {
        int add = (tid >= off) ? tmp[tid - off] : 0;
        __syncthreads();
        run += add;
        tmp[tid] = run;
        __syncthreads();
    }
    if (idx < n) offs[idx] = run - v;          // exclusive, pre-base
    if (tid == 1023) bsum[blockIdx.x] = run;   // block total
}

__global__ __launch_bounds__(128) void scan2(const int* __restrict__ bsum,
                                             int* __restrict__ bbase, int nb) {
    __shared__ int tmp[128];
    int tid = threadIdx.x;
    int v0 = (tid < nb) ? bsum[tid] : 0;
    int v = v0;
    tmp[tid] = v;
    __syncthreads();
    for (int off = 1; off < 128; off <<= 1) {
        int add = (tid >= off) ? tmp[tid - off] : 0;
        __syncthreads();
        v += add;
        tmp[tid] = v;
        __syncthreads();
    }
    if (tid < nb) bbase[tid] = v - v0;  // exclusive
}

__global__ __launch_bounds__(1024) void scan3(int* __restrict__ offs,
                                              const int* __restrict__ bbase,
                                              int* __restrict__ cursor, int n) {
    int idx = blockIdx.x * 1024 + threadIdx.x;
    if (idx < n) {
        int o = offs[idx] + bbase[blockIdx.x];
        offs[idx] = o;
        cursor[idx] = o;
    }
}

__global__ __launch_bounds__(256) void fill_kernel(const int* __restrict__ src,
                                                   const int* __restrict__ dst,
                                                   const float* __restrict__ dis,
                                                   int* __restrict__ cursor,
                                                   int2* __restrict__ edges,
                                                   int E) {
    int e = blockIdx.x * 256 + threadIdx.x;
    if (e < E) {
        int s = src[e], d = dst[e];
        int pos = atomicAdd(&cursor[d], 1);
        edges[pos] = make_int2(s, __float_as_int(dis[s] * dis[d]));
    }
}

// ---------------- W1+W2 fp32 -> fp16 in one launch ----------------

__global__ __launch_bounds__(256) void cvt_w(const float* __restrict__ W1,
                                             const float* __restrict__ W2,
                                             _Float16* __restrict__ W1h,
                                             _Float16* __restrict__ W2h) {
    int i = blockIdx.x * 256 + threadIdx.x;       // 0 .. 8191 (2 * 128*128/4)
    const int n4 = F * F / 4;
    const float* in = (i < n4) ? W1 : W2;
    _Float16* out = (i < n4) ? W1h : W2h;
    int j = (i < n4) ? i : i - n4;
    float4 v = ((const float4*)in)[j];
    half8_t h;  // only low 4 used
    h[0] = (_Float16)v.x; h[1] = (_Float16)v.y;
    h[2] = (_Float16)v.z; h[3] = (_Float16)v.w;
    *(int2*)&((_Float16*)out)[j * 4] = *(int2*)&h;
}

// ---------------- GEMM: out = A @ W.T via f16 MFMA ----------------
// Per wave: one 16-row tile x full 128 cols; W fragments register-resident.
// Layouts: A[m=lane&15][k=quad*8+j]; B[n=lane&15][k=quad*8+j] (=W[n][k]);
// C/D: col=lane&15, row=quad*4+reg.

__device__ __forceinline__ void gemm_core(const half8_t afrag[4],
                                          const _Float16* __restrict__ Wh,
                                          int m, int quad,
                                          _Float16* __restrict__ orow) {
    f32x4 acc[8];
#pragma unroll
    for (int t = 0; t < 8; ++t) acc[t] = (f32x4){0.f, 0.f, 0.f, 0.f};
#pragma unroll
    for (int c = 0; c < 4; ++c) {
#pragma unroll
        for (int t = 0; t < 8; ++t) {
            half8_t bfrag = *(const half8_t*)&Wh[(t * 16 + m) * F + c * 32 + quad * 8];
            acc[t] = __builtin_amdgcn_mfma_f32_16x16x32_f16(afrag[c], bfrag, acc[t],
                                                            0, 0, 0);
        }
    }
#pragma unroll
    for (int t = 0; t < 8; ++t)
#pragma unroll
        for (int r = 0; r < 4; ++r)
            orow[(quad * 4 + r) * F + t * 16 + m] = (_Float16)acc[t][r];
}

// layer-1 variant: A is fp32 (reads x directly, converts in-register)
__global__ __launch_bounds__(256) void gemm_a32(const float* __restrict__ A,
                                                const _Float16* __restrict__ Wh,
                                                _Float16* __restrict__ out,
                                                int ntiles) {
    int wave = threadIdx.x >> 6;
    int lane = threadIdx.x & 63;
    int tile = blockIdx.x * 4 + wave;
    if (tile >= ntiles) return;
    int m = lane & 15, quad = lane >> 4;
    const float* arow = A + (size_t)tile * 16 * F;
    half8_t afrag[4];
#pragma unroll
    for (int c = 0; c < 4; ++c) {
        float4 t0 = *(const float4*)&arow[m * F + c * 32 + quad * 8];
        float4 t1 = *(const float4*)&arow[m * F + c * 32 + quad * 8 + 4];
        afrag[c][0] = (_Float16)t0.x; afrag[c][1] = (_Float16)t0.y;
        afrag[c][2] = (_Float16)t0.z; afrag[c][3] = (_Float16)t0.w;
        afrag[c][4] = (_Float16)t1.x; afrag[c][5] = (_Float16)t1.y;
        afrag[c][6] = (_Float16)t1.z; afrag[c][7] = (_Float16)t1.w;
    }
    gemm_core(afrag, Wh, m, quad, out + (size_t)tile * 16 * F);
}

// layer-2 variant: A is fp16
__global__ __launch_bounds__(256) void gemm_a16(const _Float16* __restrict__ A,
                                                const _Float16* __restrict__ Wh,
                                                _Float16* __restrict__ out,
                                                int ntiles) {
    int wave = threadIdx.x >> 6;
    int lane = threadIdx.x & 63;
    int tile = blockIdx.x * 4 + wave;
    if (tile >= ntiles) return;
    int m = lane & 15, quad = lane >> 4;
    const _Float16* arow = A + (size_t)tile * 16 * F;
    half8_t afrag[4];
#pragma unroll
    for (int c = 0; c < 4; ++c)
        afrag[c] = *(const half8_t*)&arow[m * F + c * 32 + quad * 8];
    gemm_core(afrag, Wh, m, quad, out + (size_t)tile * 16 * F);
}

// ---------------- aggregation ----------------
// One wave per node. 16 lanes x half8 (16B) cover one 256B row; 4 edge
// groups per wave -> each gather instruction moves 4 rows (1KB/wave-inst).
// Cross-lane reduction folds the 4 groups; lanes 0-15 do the epilogue.

#define AGG_BODY(H8)                                                           \
    int node = blockIdx.x * 4 + (threadIdx.x >> 6);                            \
    int lane = threadIdx.x & 63;                                               \
    if (node >= n) return;                                                     \
    int g = lane >> 4;                                                         \
    int fo = lane & 15;                                                        \
    int beg = offs[node];                                                      \
    int end = (node + 1 < n) ? offs[node + 1] : E;                             \
    float acc[8];                                                              \
    _Pragma("unroll") for (int j = 0; j < 8; ++j) acc[j] = 0.f;                \
    for (int e = beg; e < end; e += 8) {                                       \
        int i0 = e + g, i1 = e + 4 + g;                                        \
        int2 e0 = edges[i0 < end ? i0 : end - 1];                              \
        int2 e1 = edges[i1 < end ? i1 : end - 1];                              \
        half8_t a0 = H8[(size_t)e0.x * 16 + fo];                               \
        half8_t a1 = H8[(size_t)e1.x * 16 + fo];                               \
        float w0 = (i0 < end) ? __int_as_float(e0.y) : 0.f;                    \
        float w1 = (i1 < end) ? __int_as_float(e1.y) : 0.f;                    \
        _Pragma("unroll") for (int j = 0; j < 8; ++j)                          \
            acc[j] += w0 * (float)a0[j] + w1 * (float)a1[j];                   \
    }                                                                          \
    _Pragma("unroll") for (int j = 0; j < 8; ++j) {                            \
        acc[j] += __shfl_xor(acc[j], 16);                                      \
        acc[j] += __shfl_xor(acc[j], 32);                                      \
    }                                                                          \
    if (lane >= 16) return;                                                    \
    float di = dis[node];                                                      \
    float sw = di * di;                                                        \
    half8_t hv = H8[(size_t)node * 16 + fo];                                   \
    float4 b0 = ((const float4*)bias)[fo * 2];                                 \
    float4 b1v = ((const float4*)bias)[fo * 2 + 1];                            \
    acc[0] += sw * (float)hv[0] + b0.x;  acc[1] += sw * (float)hv[1] + b0.y;   \
    acc[2] += sw * (float)hv[2] + b0.z;  acc[3] += sw * (float)hv[3] + b0.w;   \
    acc[4] += sw * (float)hv[4] + b1v.x; acc[5] += sw * (float)hv[5] + b1v.y;  \
    acc[6] += sw * (float)hv[6] + b1v.z; acc[7] += sw * (float)hv[7] + b1v.w;  \
    _Pragma("unroll") for (int j = 0; j < 8; ++j)                              \
        acc[j] = (acc[j] > 0.f) ? acc[j] : acc[j] * NEG_SLOPE;

// layer-1: writes fp16 (feeds next GEMM)
__global__ __launch_bounds__(256) void agg_to_h(const half8_t* __restrict__ h8,
                                                const float* __restrict__ dis,
                                                const float* __restrict__ bias,
                                                const int2* __restrict__ edges,
                                                const int* __restrict__ offs,
                                                half8_t* __restrict__ out,
                                                int n, int E) {
    AGG_BODY(h8)
    half8_t o;
#pragma unroll
    for (int j = 0; j < 8; ++j) o[j] = (_Float16)acc[j];
    out[(size_t)node * 16 + fo] = o;
}

// layer-2: writes fp32 (final output)
__global__ __launch_bounds__(256) void agg_to_f(const half8_t* __restrict__ h8,
                                                const float* __restrict__ dis,
                                                const float* __restrict__ bias,
                                                const int2* __restrict__ edges,
                                                const int* __restrict__ offs,
                                                float* __restrict__ out,
                                                int n, int E) {
    AGG_BODY(h8)
    float4 o0 = make_float4(acc[0], acc[1], acc[2], acc[3]);
    float4 o1 = make_float4(acc[4], acc[5], acc[6], acc[7]);
    ((float4*)out)[(size_t)node * 32 + fo * 2] = o0;
    ((float4*)out)[(size_t)node * 32 + fo * 2 + 1] = o1;
}

// ---------------- launch ----------------

static inline size_t alup(size_t x) { return (x + 255) & ~(size_t)255; }

extern "C" void kernel_launch(void* const* d_in, const int* in_sizes, int n_in,
                              void* d_out, int out_size, void* d_ws, size_t ws_size,
                              hipStream_t stream) {
    const float* x  = (const float*)d_in[0];
    const int*   ei = (const int*)d_in[1];
    const float* W1 = (const float*)d_in[2];
    const float* b1 = (const float*)d_in[3];
    const float* W2 = (const float*)d_in[4];
    const float* b2 = (const float*)d_in[5];
    float* out = (float*)d_out;

    const int N = in_sizes[0] / F;    // 100000
    const int E = in_sizes[1] / 2;    // 1600000
    const int* src = ei;
    const int* dst = ei + E;

    char* p = (char*)d_ws;
    int*      deg    = (int*)p;      p += alup((size_t)N * 4);
    int*      offs   = (int*)p;      p += alup((size_t)N * 4);
    int*      cursor = (int*)p;      p += alup((size_t)N * 4);
    int*      bsum   = (int*)p;      p += alup(128 * 4);
    int*      bbase  = (int*)p;      p += alup(128 * 4);
    float*    dis    = (float*)p;    p += alup((size_t)N * 4);
    int2*     edges  = (int2*)p;     p += alup((size_t)E * 8);
    _Float16* g      = (_Float16*)p; p += alup((size_t)N * F * 2);  // agg out L1
    _Float16* hh     = (_Float16*)p; p += alup((size_t)N * F * 2);  // gemm out
    _Float16* W1h    = (_Float16*)p; p += alup((size_t)F * F * 2);
    _Float16* W2h    = (_Float16*)p; p += alup((size_t)F * F * 2);

    const int nb = (N + 1023) / 1024;      // 98
    const int ntiles = (N + 15) / 16;      // 6250
    const int gemm_grid = (ntiles + 3) / 4;

    hipMemsetAsync(deg, 0, (size_t)N * 4, stream);
    deg_kernel<<<(E + 255) / 256, 256, 0, stream>>>(dst, deg, E);
    scan1<<<nb, 1024, 0, stream>>>(deg, offs, bsum, dis, N);
    scan2<<<1, 128, 0, stream>>>(bsum, bbase, nb);
    scan3<<<nb, 1024, 0, stream>>>(offs, bbase, cursor, N);
    fill_kernel<<<(E + 255) / 256, 256, 0, stream>>>(src, dst, dis, cursor, edges, E);
    cvt_w<<<(2 * F * F / 4 + 255) / 256, 256, 0, stream>>>(W1, W2, W1h, W2h);

    // layer 1: h = x @ W1.T (fp32 in, fp16 out), agg(+b1+lrelu) -> g (fp16)
    gemm_a32<<<gemm_grid, 256, 0, stream>>>(x, W1h, hh, ntiles);
    agg_to_h<<<(N + 3) / 4, 256, 0, stream>>>((const half8_t*)hh, dis, b1, edges,
                                              offs, (half8_t*)g, N, E);
    // layer 2: h = g @ W2.T (fp16), agg(+b2+lrelu) -> d_out (fp32)
    gemm_a16<<<gemm_grid, 256, 0, stream>>>(g, W2h, hh, ntiles);
    agg_to_f<<<(N + 3) / 4, 256, 0, stream>>>((const half8_t*)hh, dis, b2, edges,
                                              offs, out, N, E);
}